// Round 5
// baseline (522.592 us; speedup 1.0000x reference)
//
#include <hip/hip_runtime.h>
#include <hip/hip_bf16.h>
#include <stdint.h>

// WindowMSA, round 5: split pipeline.
//   wcvt:     weights f32->bf16 into ws
//   biasprep: bias5d[w][h][i][j] = bf16(rpb[rpi]+mask)   (1.84MB, L2-resident)
//   qgemm:    Q = (skip@Wskip^T+b)*scale -> ws bf16      (M=256/block)
//   kvgemm:   K,V = x@Wqkv^T+b          -> ws bf16       (M=256/block)
//   attn:     one block per window, 512thr: full-row coalesced Q/K/V reads,
//             V row-major in LDS, O staged in LDS -> coalesced write over Q
//   proj:     out = O@Wproj^T+b -> f32                   (M=256/block)

typedef __bf16 bf16;
typedef __attribute__((ext_vector_type(8))) __bf16 bf16x8;
typedef __attribute__((ext_vector_type(4))) float f32x4;

#define CDIM 192
#define NH 6
#define NTOK 49
#define QSCALE 0.17677669529663687f

// ws byte offsets
#define WSB_W      0u          // 147456 bf16 = 294912 B (wqkv | wskip | wproj)
#define WSE_WSKIP  73728u      // elem offsets within the bf16 weight blob
#define WSE_WPROJ  110592u
#define WSB_B5     294912u     // 64*6*49*49 bf16 = 1,843,968 B
#define WSB_QO     2138880u    // 200704*192 bf16 = 77,070,336 B (Q, then O)
#define WSB_K      79209216u
#define WSB_V      156279552u  // end 233,349,888

__device__ __forceinline__ uint32_t swz384(uint32_t row, uint32_t b) {
  return row * 384u + (b ^ ((row & 7u) << 4));
}
__device__ __forceinline__ uint32_t swz128(uint32_t row, uint32_t b) {
  return row * 128u + (b ^ ((row & 7u) << 4));
}
__device__ __forceinline__ uint32_t f2u(float f) { bf16 h = (bf16)f; return (uint32_t)__builtin_bit_cast(uint16_t, h); }
__device__ __forceinline__ bf16x8 lda8(const float* p) {
  float4 w0 = *(const float4*)p;
  float4 w1 = *(const float4*)(p + 4);
  bf16x8 b = {(bf16)w0.x, (bf16)w0.y, (bf16)w0.z, (bf16)w0.w,
              (bf16)w1.x, (bf16)w1.y, (bf16)w1.z, (bf16)w1.w};
  return b;
}

// ---- weights f32 -> bf16 ----
__global__ void __launch_bounds__(256)
wcvt_kernel(const float* __restrict__ wqkv, const float* __restrict__ wskip,
            const float* __restrict__ wproj, bf16* __restrict__ ws) {
  uint32_t i = (blockIdx.x * 256u + threadIdx.x) * 4u;
  float4 v;
  if (i < 73728u)       v = *(const float4*)(wqkv + i);
  else if (i < 110592u) v = *(const float4*)(wskip + (i - 73728u));
  else                  v = *(const float4*)(wproj + (i - 110592u));
  *(uint2*)(ws + i) = make_uint2((f2u(v.y) << 16) | f2u(v.x), (f2u(v.w) << 16) | f2u(v.z));
}

// ---- bias5d bf16 ----
__global__ void __launch_bounds__(256)
biasprep_kernel(const int* __restrict__ rpi, const float* __restrict__ rpb,
                const float* __restrict__ mask, bf16* __restrict__ b5) {
  uint32_t t = blockIdx.x * 256u + threadIdx.x;
  if (t >= 64u * NH * NTOK * NTOK) return;
  uint32_t w  = t / (NH * NTOK * NTOK);
  uint32_t h  = (t / (NTOK * NTOK)) % NH;
  uint32_t ij = t % (NTOK * NTOK);
  b5[t] = (bf16)(rpb[(uint32_t)rpi[ij] * NH + h] + mask[(size_t)w * (NTOK * NTOK) + ij]);
}

// ---- stage a 192x192 bf16 weight matrix into swizzled LDS ----
__device__ __forceinline__ void stage_w(char* lds, const bf16* __restrict__ w, uint32_t tid) {
  for (uint32_t u = tid; u < 4608u; u += 512u) {        // 16B units
    uint32_t row = u / 24u, c16 = u - row * 24u;
    uint4 v = *(const uint4*)(w + row * 192u + c16 * 8u);
    *(uint4*)(lds + row * 384u + ((c16 * 16u) ^ ((row & 7u) << 4))) = v;
  }
}

// ---- Q GEMM: qo = (skip @ wskip^T + b) * scale, bf16. M=256/block ----
__global__ void __launch_bounds__(512, 4)
qgemm_kernel(const float* __restrict__ skip, const bf16* __restrict__ wskip_bf,
             const float* __restrict__ bskip, bf16* __restrict__ qo, uint32_t nrows) {
  extern __shared__ char lds[];
  const uint32_t tid = threadIdx.x, lane = tid & 63u, wv = tid >> 6;
  const uint32_t l15 = lane & 15u, lg = lane >> 4;
  stage_w(lds, wskip_bf, tid);

  uint32_t rt0 = blockIdx.x * 256u + wv * 32u;
  bf16x8 af[2][6];
  #pragma unroll
  for (uint32_t mt = 0; mt < 2u; ++mt) {
    const float* ap = skip + (size_t)(rt0 + mt * 16u + l15) * CDIM + lg * 8u;
    #pragma unroll
    for (uint32_t kk = 0; kk < 6u; ++kk) af[mt][kk] = lda8(ap + kk * 32u);
  }
  __syncthreads();

  #pragma unroll
  for (uint32_t mt = 0; mt < 2u; ++mt) {
    f32x4 acc[12] = {};
    #pragma unroll
    for (uint32_t kk = 0; kk < 6u; ++kk)
      #pragma unroll
      for (uint32_t ntl = 0; ntl < 12u; ++ntl) {
        bf16x8 wb = *(const bf16x8*)(lds + swz384(ntl * 16u + l15, kk * 64u + lg * 16u));
        acc[ntl] = __builtin_amdgcn_mfma_f32_16x16x32_bf16(af[mt][kk], wb, acc[ntl], 0, 0, 0);
      }
    #pragma unroll
    for (uint32_t ntl = 0; ntl < 12u; ++ntl) {
      uint32_t ch = ntl * 16u + l15;
      float bias = bskip[ch];
      #pragma unroll
      for (uint32_t r = 0; r < 4u; ++r) {
        uint32_t row = rt0 + mt * 16u + lg * 4u + r;
        qo[(size_t)row * CDIM + ch] = (bf16)((acc[ntl][r] + bias) * QSCALE);
      }
    }
  }
}

// ---- KV GEMM: k,v = x @ wqkv^T + b, bf16. M=256/block ----
__global__ void __launch_bounds__(512, 4)
kvgemm_kernel(const float* __restrict__ x, const bf16* __restrict__ wqkv_bf,
              const float* __restrict__ bqkv, bf16* __restrict__ kbf,
              bf16* __restrict__ vbf, uint32_t nrows) {
  extern __shared__ char lds[];
  const uint32_t tid = threadIdx.x, lane = tid & 63u, wv = tid >> 6;
  const uint32_t l15 = lane & 15u, lg = lane >> 4;

  uint32_t rt0 = blockIdx.x * 256u + wv * 32u;
  bf16x8 af[2][6];
  #pragma unroll
  for (uint32_t mt = 0; mt < 2u; ++mt) {
    const float* ap = x + (size_t)(rt0 + mt * 16u + l15) * CDIM + lg * 8u;
    #pragma unroll
    for (uint32_t kk = 0; kk < 6u; ++kk) af[mt][kk] = lda8(ap + kk * 32u);
  }

  #pragma unroll
  for (uint32_t h2 = 0; h2 < 2u; ++h2) {
    if (h2) __syncthreads();                     // all reads of prev W done
    stage_w(lds, wqkv_bf + h2 * 36864u, tid);
    __syncthreads();
    bf16* dst = h2 ? vbf : kbf;
    #pragma unroll
    for (uint32_t mt = 0; mt < 2u; ++mt) {
      f32x4 acc[12] = {};
      #pragma unroll
      for (uint32_t kk = 0; kk < 6u; ++kk)
        #pragma unroll
        for (uint32_t ntl = 0; ntl < 12u; ++ntl) {
          bf16x8 wb = *(const bf16x8*)(lds + swz384(ntl * 16u + l15, kk * 64u + lg * 16u));
          acc[ntl] = __builtin_amdgcn_mfma_f32_16x16x32_bf16(af[mt][kk], wb, acc[ntl], 0, 0, 0);
        }
      #pragma unroll
      for (uint32_t ntl = 0; ntl < 12u; ++ntl) {
        uint32_t ch = ntl * 16u + l15;
        float bias = bqkv[h2 * CDIM + ch];
        #pragma unroll
        for (uint32_t r = 0; r < 4u; ++r) {
          uint32_t row = rt0 + mt * 16u + lg * 4u + r;
          dst[(size_t)row * CDIM + ch] = (bf16)(acc[ntl][r] + bias);
        }
      }
    }
  }
}

// ---- attention: one block per window. LDS: V rows 24576 + 8 strips 16384 ----
__global__ void __launch_bounds__(512, 6)
attn_kernel(bf16* __restrict__ qo, const bf16* __restrict__ kbf,
            const bf16* __restrict__ vbf, const bf16* __restrict__ b5bf) {
  extern __shared__ char lds[];
  const uint32_t tid = threadIdx.x, lane = tid & 63u, wv = tid >> 6;
  const uint32_t l15 = lane & 15u, lg = lane >> 4;
  const uint32_t grp = wv >> 2, st = wv & 3u;
  const uint32_t win = blockIdx.x;
  char* strip = lds + 24576u + wv * 2048u;
  const size_t wrow0 = (size_t)win * NTOK;

  // stage V row-major [64][384B] swizzled; coalesced uint4 copies
  for (uint32_t i = tid; i < 1176u; i += 512u) {         // 49 rows x 24 chunks
    uint32_t tok = i / 24u, c16 = i - tok * 24u;
    uint4 v = *(const uint4*)(vbf + (wrow0 + tok) * CDIM + c16 * 8u);
    *(uint4*)(lds + swz384(tok, c16 * 16u)) = v;
  }
  for (uint32_t i = tid; i < 360u; i += 512u) {          // zero pad rows 49..63
    uint32_t tok = 49u + i / 24u, c16 = i % 24u;
    *(uint4*)(lds + swz384(tok, c16 * 16u)) = make_uint4(0u, 0u, 0u, 0u);
  }
  __syncthreads();

  f32x4 oacc[3][2];
  uint32_t qrow = st * 16u + l15; if (qrow > 48u) qrow = 48u;

  #pragma unroll
  for (uint32_t hl = 0; hl < 3u; ++hl) {
    uint32_t h = grp * 3u + hl;
    bf16x8 qa = *(const bf16x8*)(qo + (wrow0 + qrow) * CDIM + h * 32u + lg * 8u);
    f32x4 s[4];
    #pragma unroll
    for (uint32_t nt = 0; nt < 4u; ++nt) {
      uint32_t krow = nt * 16u + l15; if (krow > 48u) krow = 48u;
      bf16x8 kb = *(const bf16x8*)(kbf + (wrow0 + krow) * CDIM + h * 32u + lg * 8u);
      f32x4 z = {};
      s[nt] = __builtin_amdgcn_mfma_f32_16x16x32_bf16(qa, kb, z, 0, 0, 0);
    }
    const bf16* b5 = b5bf + ((size_t)(win & 63u) * NH + h) * (NTOK * NTOK);
    #pragma unroll
    for (uint32_t nt = 0; nt < 4u; ++nt) {
      uint32_t j = nt * 16u + l15;
      #pragma unroll
      for (uint32_t r = 0; r < 4u; ++r) {
        uint32_t i = st * 16u + lg * 4u + r;
        float v = s[nt][r];
        if (j < NTOK) { if (i < NTOK) v += (float)b5[i * NTOK + j]; }
        else v = -1e30f;
        s[nt][r] = v;
      }
    }
    #pragma unroll
    for (uint32_t r = 0; r < 4u; ++r) {
      float mm = fmaxf(fmaxf(s[0][r], s[1][r]), fmaxf(s[2][r], s[3][r]));
      mm = fmaxf(mm, __shfl_xor(mm, 1)); mm = fmaxf(mm, __shfl_xor(mm, 2));
      mm = fmaxf(mm, __shfl_xor(mm, 4)); mm = fmaxf(mm, __shfl_xor(mm, 8));
      float ss = 0.f;
      #pragma unroll
      for (uint32_t nt = 0; nt < 4u; ++nt) { float p = __expf(s[nt][r] - mm); s[nt][r] = p; ss += p; }
      ss += __shfl_xor(ss, 1); ss += __shfl_xor(ss, 2);
      ss += __shfl_xor(ss, 4); ss += __shfl_xor(ss, 8);
      float inv = 1.f / ss;
      #pragma unroll
      for (uint32_t nt = 0; nt < 4u; ++nt) s[nt][r] *= inv;
    }
    // P (D-layout) -> private strip -> A-layout (same wave, no barrier)
    #pragma unroll
    for (uint32_t nt = 0; nt < 4u; ++nt) {
      uint32_t colb = (nt * 16u + l15) * 2u;
      #pragma unroll
      for (uint32_t r = 0; r < 4u; ++r)
        *(bf16*)(strip + swz128(lg * 4u + r, colb)) = (bf16)s[nt][r];
    }
    bf16x8 pa0 = *(const bf16x8*)(strip + swz128(l15, lg * 16u));
    bf16x8 pa1 = *(const bf16x8*)(strip + swz128(l15, 64u + lg * 16u));
    #pragma unroll
    for (uint32_t nt2 = 0; nt2 < 2u; ++nt2) {
      uint32_t ch = h * 32u + nt2 * 16u + l15;
      bf16x8 vb0, vb1;
      #pragma unroll
      for (uint32_t j = 0; j < 8u; ++j) {
        vb0[j] = *(const bf16*)(lds + swz384(lg * 8u + j, ch * 2u));
        vb1[j] = *(const bf16*)(lds + swz384(32u + lg * 8u + j, ch * 2u));
      }
      f32x4 z = {};
      f32x4 o = __builtin_amdgcn_mfma_f32_16x16x32_bf16(pa0, vb0, z, 0, 0, 0);
      oacc[hl][nt2] = __builtin_amdgcn_mfma_f32_16x16x32_bf16(pa1, vb1, o, 0, 0, 0);
    }
  }

  __syncthreads();   // all V reads + Q reads done -> reuse V region for O

  #pragma unroll
  for (uint32_t hl = 0; hl < 3u; ++hl)
    #pragma unroll
    for (uint32_t nt2 = 0; nt2 < 2u; ++nt2) {
      uint32_t ch = (grp * 3u + hl) * 32u + nt2 * 16u + l15;
      #pragma unroll
      for (uint32_t r = 0; r < 4u; ++r)
        *(bf16*)(lds + swz384(st * 16u + lg * 4u + r, ch * 2u)) = (bf16)oacc[hl][nt2][r];
    }

  __syncthreads();   // O tile ready -> coalesced write over Q

  for (uint32_t i = tid; i < 1176u; i += 512u) {
    uint32_t tok = i / 24u, c16 = i - tok * 24u;
    uint4 v = *(const uint4*)(lds + swz384(tok, c16 * 16u));
    *(uint4*)(qo + (wrow0 + tok) * CDIM + c16 * 8u) = v;
  }
}

// ---- proj GEMM: out = O @ wproj^T + b, f32. M=256/block ----
__global__ void __launch_bounds__(512, 4)
proj_kernel(const bf16* __restrict__ qo, const bf16* __restrict__ wproj_bf,
            const float* __restrict__ bproj, float* __restrict__ out, uint32_t nrows) {
  extern __shared__ char lds[];
  const uint32_t tid = threadIdx.x, lane = tid & 63u, wv = tid >> 6;
  const uint32_t l15 = lane & 15u, lg = lane >> 4;
  stage_w(lds, wproj_bf, tid);

  uint32_t rt0 = blockIdx.x * 256u + wv * 32u;
  bf16x8 af[2][6];
  #pragma unroll
  for (uint32_t mt = 0; mt < 2u; ++mt) {
    const bf16* ap = qo + (size_t)(rt0 + mt * 16u + l15) * CDIM + lg * 8u;
    #pragma unroll
    for (uint32_t kk = 0; kk < 6u; ++kk) af[mt][kk] = *(const bf16x8*)(ap + kk * 32u);
  }
  __syncthreads();

  #pragma unroll
  for (uint32_t mt = 0; mt < 2u; ++mt) {
    f32x4 acc[12] = {};
    #pragma unroll
    for (uint32_t kk = 0; kk < 6u; ++kk)
      #pragma unroll
      for (uint32_t ntl = 0; ntl < 12u; ++ntl) {
        bf16x8 wb = *(const bf16x8*)(lds + swz384(ntl * 16u + l15, kk * 64u + lg * 16u));
        acc[ntl] = __builtin_amdgcn_mfma_f32_16x16x32_bf16(af[mt][kk], wb, acc[ntl], 0, 0, 0);
      }
    #pragma unroll
    for (uint32_t ntl = 0; ntl < 12u; ++ntl) {
      uint32_t ch = ntl * 16u + l15;
      float bias = bproj[ch];
      #pragma unroll
      for (uint32_t r = 0; r < 4u; ++r) {
        uint32_t row = rt0 + mt * 16u + lg * 4u + r;
        out[(size_t)row * CDIM + ch] = acc[ntl][r] + bias;
      }
    }
  }
}

extern "C" void kernel_launch(void* const* d_in, const int* in_sizes, int n_in,
                              void* d_out, int out_size, void* d_ws, size_t ws_size,
                              hipStream_t stream) {
  const float* x     = (const float*)d_in[0];
  const float* skip  = (const float*)d_in[1];
  const float* mask  = (const float*)d_in[2];
  const int*   rpi   = (const int*)  d_in[3];
  const float* rpb   = (const float*)d_in[4];
  const float* wqkv  = (const float*)d_in[5];
  const float* bqkv  = (const float*)d_in[6];
  const float* wskip = (const float*)d_in[7];
  const float* bskip = (const float*)d_in[8];
  const float* wproj = (const float*)d_in[9];
  const float* bproj = (const float*)d_in[10];

  char* ws = (char*)d_ws;
  bf16* wbf  = (bf16*)(ws + WSB_W);
  bf16* b5bf = (bf16*)(ws + WSB_B5);
  bf16* qo   = (bf16*)(ws + WSB_QO);
  bf16* kbf  = (bf16*)(ws + WSB_K);
  bf16* vbf  = (bf16*)(ws + WSB_V);

  uint32_t nwin  = (uint32_t)(in_sizes[0] / (NTOK * CDIM));
  uint32_t nrows = nwin * NTOK;
  uint32_t ngb   = (nrows + 255u) / 256u;

  hipFuncSetAttribute((const void*)qgemm_kernel,  hipFuncAttributeMaxDynamicSharedMemorySize, 73728);
  hipFuncSetAttribute((const void*)kvgemm_kernel, hipFuncAttributeMaxDynamicSharedMemorySize, 73728);
  hipFuncSetAttribute((const void*)proj_kernel,   hipFuncAttributeMaxDynamicSharedMemorySize, 73728);

  wcvt_kernel<<<144, 256, 0, stream>>>(wqkv, wskip, wproj, wbf);
  biasprep_kernel<<<(64u * NH * NTOK * NTOK + 255u) / 256u, 256, 0, stream>>>(rpi, rpb, mask, b5bf);
  qgemm_kernel<<<ngb, 512, 73728, stream>>>(skip, wbf + WSE_WSKIP, bskip, qo, nrows);
  kvgemm_kernel<<<ngb, 512, 73728, stream>>>(x, wbf, bqkv, kbf, vbf, nrows);
  attn_kernel<<<nwin, 512, 40960, stream>>>(qo, kbf, vbf, b5bf);
  proj_kernel<<<ngb, 512, 73728, stream>>>(qo, wbf + WSE_WPROJ, bproj, (float*)d_out, nrows);
}

// Round 6
// 376.537 us; speedup vs baseline: 1.3879x; 1.3879x over previous
//
#include <hip/hip_runtime.h>
#include <hip/hip_bf16.h>
#include <stdint.h>

// WindowMSA, round 6: split pipeline; GEMM bf16 outputs staged through an LDS
// transpose (reusing the dead weight region) so global writes are fully
// coalesced 16B rows (fixes the 2.2x write amplification of 32B D-layout
// chunk stores). GEMMs back to M=128 (round-5's M=256 spilled: VGPR=64 forced).
//   wcvt:     weights f32->bf16 into ws
//   biasprep: bias5d bf16 (1.84MB, L2-resident)
//   qgemm:    Q = (skip@Wskip^T+b)*scale -> ws bf16   (M=128, LDS-transposed store)
//   kvgemm:   K,V = x@Wqkv^T+b -> ws bf16             (M=128, LDS-transposed store x2)
//   attn:     one block per window (unchanged from r5)
//   proj:     out = O@Wproj^T+b -> f32 direct stores (64B chunks; verify WRITE_SIZE)

typedef __bf16 bf16;
typedef __attribute__((ext_vector_type(8))) __bf16 bf16x8;
typedef __attribute__((ext_vector_type(4))) float f32x4;

#define CDIM 192
#define NH 6
#define NTOK 49
#define QSCALE 0.17677669529663687f

// ws byte offsets
#define WSB_W      0u          // 147456 bf16 = 294912 B (wqkv | wskip | wproj)
#define WSE_WSKIP  73728u      // elem offsets within the bf16 weight blob
#define WSE_WPROJ  110592u
#define WSB_B5     294912u     // 64*6*49*49 bf16 = 1,843,968 B
#define WSB_QO     2138880u    // 200704*192 bf16 = 77,070,336 B (Q, then O)
#define WSB_K      79209216u
#define WSB_V      156279552u  // end 233,349,888

#define TSTRIDE 400u           // transpose buffer row stride (16B-aligned, bank-spread)

__device__ __forceinline__ uint32_t swz384(uint32_t row, uint32_t b) {
  return row * 384u + (b ^ ((row & 7u) << 4));
}
__device__ __forceinline__ uint32_t swz128(uint32_t row, uint32_t b) {
  return row * 128u + (b ^ ((row & 7u) << 4));
}
__device__ __forceinline__ uint32_t f2u(float f) { bf16 h = (bf16)f; return (uint32_t)__builtin_bit_cast(uint16_t, h); }
__device__ __forceinline__ bf16x8 lda8(const float* p) {
  float4 w0 = *(const float4*)p;
  float4 w1 = *(const float4*)(p + 4);
  bf16x8 b = {(bf16)w0.x, (bf16)w0.y, (bf16)w0.z, (bf16)w0.w,
              (bf16)w1.x, (bf16)w1.y, (bf16)w1.z, (bf16)w1.w};
  return b;
}

// ---- weights f32 -> bf16 ----
__global__ void __launch_bounds__(256)
wcvt_kernel(const float* __restrict__ wqkv, const float* __restrict__ wskip,
            const float* __restrict__ wproj, bf16* __restrict__ ws) {
  uint32_t i = (blockIdx.x * 256u + threadIdx.x) * 4u;
  float4 v;
  if (i < 73728u)       v = *(const float4*)(wqkv + i);
  else if (i < 110592u) v = *(const float4*)(wskip + (i - 73728u));
  else                  v = *(const float4*)(wproj + (i - 110592u));
  *(uint2*)(ws + i) = make_uint2((f2u(v.y) << 16) | f2u(v.x), (f2u(v.w) << 16) | f2u(v.z));
}

// ---- bias5d bf16 ----
__global__ void __launch_bounds__(256)
biasprep_kernel(const int* __restrict__ rpi, const float* __restrict__ rpb,
                const float* __restrict__ mask, bf16* __restrict__ b5) {
  uint32_t t = blockIdx.x * 256u + threadIdx.x;
  if (t >= 64u * NH * NTOK * NTOK) return;
  uint32_t w  = t / (NH * NTOK * NTOK);
  uint32_t h  = (t / (NTOK * NTOK)) % NH;
  uint32_t ij = t % (NTOK * NTOK);
  b5[t] = (bf16)(rpb[(uint32_t)rpi[ij] * NH + h] + mask[(size_t)w * (NTOK * NTOK) + ij]);
}

// ---- stage a 192x192 bf16 weight matrix into swizzled LDS ----
__device__ __forceinline__ void stage_w(char* lds, const bf16* __restrict__ w, uint32_t tid) {
  for (uint32_t u = tid; u < 4608u; u += 512u) {        // 16B units
    uint32_t row = u / 24u, c16 = u - row * 24u;
    uint4 v = *(const uint4*)(w + row * 192u + c16 * 8u);
    *(uint4*)(lds + row * 384u + ((c16 * 16u) ^ ((row & 7u) << 4))) = v;
  }
}

// ---- transpose acc tiles into LDS rows, then coalesced copy to global ----
// acc[ntl][r]: row16 = lg*4+r, ch = ntl*16+l15. Buffer: [128][TSTRIDE] bytes.
__device__ __forceinline__ void store_tile_bf16(
    char* lds, const f32x4* acc, const float* __restrict__ bias_base,
    bf16* __restrict__ dst, uint32_t rowbase, uint32_t wv, uint32_t l15,
    uint32_t lg, uint32_t tid, float scale) {
  #pragma unroll
  for (uint32_t ntl = 0; ntl < 12u; ++ntl) {
    float bias = bias_base[ntl * 16u + l15];
    #pragma unroll
    for (uint32_t r = 0; r < 4u; ++r) {
      uint32_t trow = wv * 16u + lg * 4u + r;
      *(bf16*)(lds + trow * TSTRIDE + (ntl * 16u + l15) * 2u) =
          (bf16)((acc[ntl][r] + bias) * scale);
    }
  }
  __syncthreads();   // transpose tile ready
  for (uint32_t i = tid; i < 3072u; i += 512u) {        // 128 rows x 24 uint4
    uint32_t row = i / 24u, c16 = i - row * 24u;
    uint4 v = *(const uint4*)(lds + row * TSTRIDE + c16 * 16u);
    *(uint4*)(dst + (size_t)(rowbase + row) * CDIM + c16 * 8u) = v;
  }
}

// ---- Q GEMM: qo = (skip @ wskip^T + b) * scale, bf16. M=128/block ----
__global__ void __launch_bounds__(512, 4)
qgemm_kernel(const float* __restrict__ skip, const bf16* __restrict__ wskip_bf,
             const float* __restrict__ bskip, bf16* __restrict__ qo) {
  extern __shared__ char lds[];
  const uint32_t tid = threadIdx.x, lane = tid & 63u, wv = tid >> 6;
  const uint32_t l15 = lane & 15u, lg = lane >> 4;
  stage_w(lds, wskip_bf, tid);

  uint32_t rowbase = blockIdx.x * 128u;
  const float* ap = skip + (size_t)(rowbase + wv * 16u + l15) * CDIM + lg * 8u;
  bf16x8 af[6];
  #pragma unroll
  for (uint32_t kk = 0; kk < 6u; ++kk) af[kk] = lda8(ap + kk * 32u);
  __syncthreads();

  f32x4 acc[12] = {};
  #pragma unroll
  for (uint32_t kk = 0; kk < 6u; ++kk)
    #pragma unroll
    for (uint32_t ntl = 0; ntl < 12u; ++ntl) {
      bf16x8 wb = *(const bf16x8*)(lds + swz384(ntl * 16u + l15, kk * 64u + lg * 16u));
      acc[ntl] = __builtin_amdgcn_mfma_f32_16x16x32_bf16(af[kk], wb, acc[ntl], 0, 0, 0);
    }
  __syncthreads();   // W dead -> reuse region as transpose buffer
  store_tile_bf16(lds, acc, bskip, qo, rowbase, wv, l15, lg, tid, QSCALE);
}

// ---- KV GEMM: k,v = x @ wqkv^T + b, bf16. M=128/block ----
__global__ void __launch_bounds__(512, 4)
kvgemm_kernel(const float* __restrict__ x, const bf16* __restrict__ wqkv_bf,
              const float* __restrict__ bqkv, bf16* __restrict__ kbf,
              bf16* __restrict__ vbf) {
  extern __shared__ char lds[];
  const uint32_t tid = threadIdx.x, lane = tid & 63u, wv = tid >> 6;
  const uint32_t l15 = lane & 15u, lg = lane >> 4;

  uint32_t rowbase = blockIdx.x * 128u;
  const float* ap = x + (size_t)(rowbase + wv * 16u + l15) * CDIM + lg * 8u;
  bf16x8 af[6];
  #pragma unroll
  for (uint32_t kk = 0; kk < 6u; ++kk) af[kk] = lda8(ap + kk * 32u);

  #pragma unroll
  for (uint32_t h2 = 0; h2 < 2u; ++h2) {
    if (h2) __syncthreads();                 // copy-out of K done before restage
    stage_w(lds, wqkv_bf + h2 * 36864u, tid);
    __syncthreads();
    f32x4 acc[12] = {};
    #pragma unroll
    for (uint32_t kk = 0; kk < 6u; ++kk)
      #pragma unroll
      for (uint32_t ntl = 0; ntl < 12u; ++ntl) {
        bf16x8 wb = *(const bf16x8*)(lds + swz384(ntl * 16u + l15, kk * 64u + lg * 16u));
        acc[ntl] = __builtin_amdgcn_mfma_f32_16x16x32_bf16(af[kk], wb, acc[ntl], 0, 0, 0);
      }
    __syncthreads();   // W dead -> transpose buffer
    store_tile_bf16(lds, acc, bqkv + h2 * CDIM, h2 ? vbf : kbf, rowbase,
                    wv, l15, lg, tid, 1.0f);
  }
}

// ---- attention: one block per window. LDS: V rows 24576 + 8 strips 16384 ----
__global__ void __launch_bounds__(512, 6)
attn_kernel(bf16* __restrict__ qo, const bf16* __restrict__ kbf,
            const bf16* __restrict__ vbf, const bf16* __restrict__ b5bf) {
  extern __shared__ char lds[];
  const uint32_t tid = threadIdx.x, lane = tid & 63u, wv = tid >> 6;
  const uint32_t l15 = lane & 15u, lg = lane >> 4;
  const uint32_t grp = wv >> 2, st = wv & 3u;
  const uint32_t win = blockIdx.x;
  char* strip = lds + 24576u + wv * 2048u;
  const size_t wrow0 = (size_t)win * NTOK;

  // stage V row-major [64][384B] swizzled; coalesced uint4 copies
  for (uint32_t i = tid; i < 1176u; i += 512u) {         // 49 rows x 24 chunks
    uint32_t tok = i / 24u, c16 = i - tok * 24u;
    uint4 v = *(const uint4*)(vbf + (wrow0 + tok) * CDIM + c16 * 8u);
    *(uint4*)(lds + swz384(tok, c16 * 16u)) = v;
  }
  for (uint32_t i = tid; i < 360u; i += 512u) {          // zero pad rows 49..63
    uint32_t tok = 49u + i / 24u, c16 = i % 24u;
    *(uint4*)(lds + swz384(tok, c16 * 16u)) = make_uint4(0u, 0u, 0u, 0u);
  }
  __syncthreads();

  f32x4 oacc[3][2];
  uint32_t qrow = st * 16u + l15; if (qrow > 48u) qrow = 48u;

  #pragma unroll
  for (uint32_t hl = 0; hl < 3u; ++hl) {
    uint32_t h = grp * 3u + hl;
    bf16x8 qa = *(const bf16x8*)(qo + (wrow0 + qrow) * CDIM + h * 32u + lg * 8u);
    f32x4 s[4];
    #pragma unroll
    for (uint32_t nt = 0; nt < 4u; ++nt) {
      uint32_t krow = nt * 16u + l15; if (krow > 48u) krow = 48u;
      bf16x8 kb = *(const bf16x8*)(kbf + (wrow0 + krow) * CDIM + h * 32u + lg * 8u);
      f32x4 z = {};
      s[nt] = __builtin_amdgcn_mfma_f32_16x16x32_bf16(qa, kb, z, 0, 0, 0);
    }
    const bf16* b5 = b5bf + ((size_t)(win & 63u) * NH + h) * (NTOK * NTOK);
    #pragma unroll
    for (uint32_t nt = 0; nt < 4u; ++nt) {
      uint32_t j = nt * 16u + l15;
      #pragma unroll
      for (uint32_t r = 0; r < 4u; ++r) {
        uint32_t i = st * 16u + lg * 4u + r;
        float v = s[nt][r];
        if (j < NTOK) { if (i < NTOK) v += (float)b5[i * NTOK + j]; }
        else v = -1e30f;
        s[nt][r] = v;
      }
    }
    #pragma unroll
    for (uint32_t r = 0; r < 4u; ++r) {
      float mm = fmaxf(fmaxf(s[0][r], s[1][r]), fmaxf(s[2][r], s[3][r]));
      mm = fmaxf(mm, __shfl_xor(mm, 1)); mm = fmaxf(mm, __shfl_xor(mm, 2));
      mm = fmaxf(mm, __shfl_xor(mm, 4)); mm = fmaxf(mm, __shfl_xor(mm, 8));
      float ss = 0.f;
      #pragma unroll
      for (uint32_t nt = 0; nt < 4u; ++nt) { float p = __expf(s[nt][r] - mm); s[nt][r] = p; ss += p; }
      ss += __shfl_xor(ss, 1); ss += __shfl_xor(ss, 2);
      ss += __shfl_xor(ss, 4); ss += __shfl_xor(ss, 8);
      float inv = 1.f / ss;
      #pragma unroll
      for (uint32_t nt = 0; nt < 4u; ++nt) s[nt][r] *= inv;
    }
    // P (D-layout) -> private strip -> A-layout (same wave, no barrier)
    #pragma unroll
    for (uint32_t nt = 0; nt < 4u; ++nt) {
      uint32_t colb = (nt * 16u + l15) * 2u;
      #pragma unroll
      for (uint32_t r = 0; r < 4u; ++r)
        *(bf16*)(strip + swz128(lg * 4u + r, colb)) = (bf16)s[nt][r];
    }
    bf16x8 pa0 = *(const bf16x8*)(strip + swz128(l15, lg * 16u));
    bf16x8 pa1 = *(const bf16x8*)(strip + swz128(l15, 64u + lg * 16u));
    #pragma unroll
    for (uint32_t nt2 = 0; nt2 < 2u; ++nt2) {
      uint32_t ch = h * 32u + nt2 * 16u + l15;
      bf16x8 vb0, vb1;
      #pragma unroll
      for (uint32_t j = 0; j < 8u; ++j) {
        vb0[j] = *(const bf16*)(lds + swz384(lg * 8u + j, ch * 2u));
        vb1[j] = *(const bf16*)(lds + swz384(32u + lg * 8u + j, ch * 2u));
      }
      f32x4 z = {};
      f32x4 o = __builtin_amdgcn_mfma_f32_16x16x32_bf16(pa0, vb0, z, 0, 0, 0);
      oacc[hl][nt2] = __builtin_amdgcn_mfma_f32_16x16x32_bf16(pa1, vb1, o, 0, 0, 0);
    }
  }

  __syncthreads();   // all V reads + Q reads done -> reuse V region for O

  #pragma unroll
  for (uint32_t hl = 0; hl < 3u; ++hl)
    #pragma unroll
    for (uint32_t nt2 = 0; nt2 < 2u; ++nt2) {
      uint32_t ch = (grp * 3u + hl) * 32u + nt2 * 16u + l15;
      #pragma unroll
      for (uint32_t r = 0; r < 4u; ++r)
        *(bf16*)(lds + swz384(st * 16u + lg * 4u + r, ch * 2u)) = (bf16)oacc[hl][nt2][r];
    }

  __syncthreads();   // O tile ready -> coalesced write over Q

  for (uint32_t i = tid; i < 1176u; i += 512u) {
    uint32_t tok = i / 24u, c16 = i - tok * 24u;
    uint4 v = *(const uint4*)(lds + swz384(tok, c16 * 16u));
    *(uint4*)(qo + (wrow0 + tok) * CDIM + c16 * 8u) = v;
  }
}

// ---- proj GEMM: out = O @ wproj^T + b, f32. M=128/block, direct stores ----
__global__ void __launch_bounds__(512, 4)
proj_kernel(const bf16* __restrict__ qo, const bf16* __restrict__ wproj_bf,
            const float* __restrict__ bproj, float* __restrict__ out) {
  extern __shared__ char lds[];
  const uint32_t tid = threadIdx.x, lane = tid & 63u, wv = tid >> 6;
  const uint32_t l15 = lane & 15u, lg = lane >> 4;
  stage_w(lds, wproj_bf, tid);

  uint32_t rowbase = blockIdx.x * 128u;
  const bf16* ap = qo + (size_t)(rowbase + wv * 16u + l15) * CDIM + lg * 8u;
  bf16x8 af[6];
  #pragma unroll
  for (uint32_t kk = 0; kk < 6u; ++kk) af[kk] = *(const bf16x8*)(ap + kk * 32u);
  __syncthreads();

  f32x4 acc[12] = {};
  #pragma unroll
  for (uint32_t kk = 0; kk < 6u; ++kk)
    #pragma unroll
    for (uint32_t ntl = 0; ntl < 12u; ++ntl) {
      bf16x8 wb = *(const bf16x8*)(lds + swz384(ntl * 16u + l15, kk * 64u + lg * 16u));
      acc[ntl] = __builtin_amdgcn_mfma_f32_16x16x32_bf16(af[kk], wb, acc[ntl], 0, 0, 0);
    }
  #pragma unroll
  for (uint32_t ntl = 0; ntl < 12u; ++ntl) {
    uint32_t ch = ntl * 16u + l15;
    float bias = bproj[ch];
    #pragma unroll
    for (uint32_t r = 0; r < 4u; ++r) {
      uint32_t row = rowbase + wv * 16u + lg * 4u + r;
      out[(size_t)row * CDIM + ch] = acc[ntl][r] + bias;
    }
  }
}

extern "C" void kernel_launch(void* const* d_in, const int* in_sizes, int n_in,
                              void* d_out, int out_size, void* d_ws, size_t ws_size,
                              hipStream_t stream) {
  const float* x     = (const float*)d_in[0];
  const float* skip  = (const float*)d_in[1];
  const float* mask  = (const float*)d_in[2];
  const int*   rpi   = (const int*)  d_in[3];
  const float* rpb   = (const float*)d_in[4];
  const float* wqkv  = (const float*)d_in[5];
  const float* bqkv  = (const float*)d_in[6];
  const float* wskip = (const float*)d_in[7];
  const float* bskip = (const float*)d_in[8];
  const float* wproj = (const float*)d_in[9];
  const float* bproj = (const float*)d_in[10];

  char* ws = (char*)d_ws;
  bf16* wbf  = (bf16*)(ws + WSB_W);
  bf16* b5bf = (bf16*)(ws + WSB_B5);
  bf16* qo   = (bf16*)(ws + WSB_QO);
  bf16* kbf  = (bf16*)(ws + WSB_K);
  bf16* vbf  = (bf16*)(ws + WSB_V);

  uint32_t nwin  = (uint32_t)(in_sizes[0] / (NTOK * CDIM));
  uint32_t nrows = nwin * NTOK;            // 200704, divisible by 128
  uint32_t ngb   = nrows / 128u;

  hipFuncSetAttribute((const void*)qgemm_kernel,  hipFuncAttributeMaxDynamicSharedMemorySize, 73728);
  hipFuncSetAttribute((const void*)kvgemm_kernel, hipFuncAttributeMaxDynamicSharedMemorySize, 73728);
  hipFuncSetAttribute((const void*)proj_kernel,   hipFuncAttributeMaxDynamicSharedMemorySize, 73728);

  wcvt_kernel<<<144, 256, 0, stream>>>(wqkv, wskip, wproj, wbf);
  biasprep_kernel<<<(64u * NH * NTOK * NTOK + 255u) / 256u, 256, 0, stream>>>(rpi, rpb, mask, b5bf);
  qgemm_kernel<<<ngb, 512, 73728, stream>>>(skip, wbf + WSE_WSKIP, bskip, qo);
  kvgemm_kernel<<<ngb, 512, 73728, stream>>>(x, wbf, bqkv, kbf, vbf);
  attn_kernel<<<nwin, 512, 40960, stream>>>(qo, kbf, vbf, b5bf);
  proj_kernel<<<ngb, 512, 73728, stream>>>(qo, wbf + WSE_WPROJ, bproj, (float*)d_out);
}

// Round 8
// 356.508 us; speedup vs baseline: 1.4659x; 1.0562x over previous
//
#include <hip/hip_runtime.h>
#include <hip/hip_bf16.h>
#include <stdint.h>

// WindowMSA, round 8: round-7 design with the VT-layout bug fixed.
//  - r7 bug: voff stagger ((ch>>4)&7)*16 WRAPPED at ch=128 -> rows 127/128
//    overlapped in LDS (V corruption, absmax 1.3e-2). Also stride 136 made
//    odd-channel ds_read_b128 16B-misaligned.
//  - fix: voff(ch) = ch*144 + (ch>>4)*16 (monotone stagger): no overlap,
//    16B-aligned, read-conflict-optimal (stride ≡ 4 dwords mod 32 tiles all
//    32 banks at 2 lanes/bank), write stagger preserved.
// Rest identical to round 7.

typedef __bf16 bf16;
typedef __attribute__((ext_vector_type(8))) __bf16 bf16x8;
typedef __attribute__((ext_vector_type(4))) float f32x4;

#define CDIM 192
#define NH 6
#define NTOK 49
#define QSCALE 0.17677669529663687f

// ws byte offsets
#define WSB_W      0u          // 147456 bf16 = 294912 B (wqkv | wskip | wproj)
#define WSE_WSKIP  73728u      // elem offsets within the bf16 weight blob
#define WSE_WPROJ  110592u
#define WSB_B5     294912u     // b5L: 64*6*16*256 bf16 = 3,145,728 B
#define WSB_QO     3440640u    // 200704*192 bf16 = 77,070,336 B (Q, then O)
#define WSB_K      80510976u
#define WSB_V      157581312u  // end 234,651,648

#define TSTRIDE 400u           // GEMM transpose buffer row stride

// attn LDS: VT region (voff(191)+128 = 27808), strips after
#define OFF_STRIP 27904u
#define ATTN_LDS  44288u       // 27904 + 8*2048

__device__ __forceinline__ uint32_t swz384(uint32_t row, uint32_t b) {
  return row * 384u + (b ^ ((row & 7u) << 4));
}
__device__ __forceinline__ uint32_t swz128(uint32_t row, uint32_t b) {
  return row * 128u + (b ^ ((row & 7u) << 4));
}
__device__ __forceinline__ uint32_t voff(uint32_t ch) {   // VT row base, 16B-aligned, monotone
  return ch * 144u + ((ch >> 4) << 4);
}
__device__ __forceinline__ uint32_t f2u(float f) { bf16 h = (bf16)f; return (uint32_t)__builtin_bit_cast(uint16_t, h); }
__device__ __forceinline__ bf16x8 lda8(const float* p) {
  float4 w0 = *(const float4*)p;
  float4 w1 = *(const float4*)(p + 4);
  bf16x8 b = {(bf16)w0.x, (bf16)w0.y, (bf16)w0.z, (bf16)w0.w,
              (bf16)w1.x, (bf16)w1.y, (bf16)w1.z, (bf16)w1.w};
  return b;
}
__device__ __forceinline__ float bfu2f(uint32_t lo16) { return __builtin_bit_cast(float, lo16 << 16); }
__device__ __forceinline__ float bfh2f(uint32_t hi16) { return __builtin_bit_cast(float, hi16 & 0xffff0000u); }

// ---- weights f32 -> bf16 ----
__global__ void __launch_bounds__(256)
wcvt_kernel(const float* __restrict__ wqkv, const float* __restrict__ wskip,
            const float* __restrict__ wproj, bf16* __restrict__ ws) {
  uint32_t i = (blockIdx.x * 256u + threadIdx.x) * 4u;
  float4 v;
  if (i < 73728u)       v = *(const float4*)(wqkv + i);
  else if (i < 110592u) v = *(const float4*)(wskip + (i - 73728u));
  else                  v = *(const float4*)(wproj + (i - 110592u));
  *(uint2*)(ws + i) = make_uint2((f2u(v.y) << 16) | f2u(v.x), (f2u(v.w) << 16) | f2u(v.z));
}

// ---- bias in MFMA D-layout order: t = (((w*6+h)*16 + st*4+nt)*64 + lane)*4 + r ----
__global__ void __launch_bounds__(256)
biasprep_kernel(const int* __restrict__ rpi, const float* __restrict__ rpb,
                const float* __restrict__ mask, bf16* __restrict__ b5) {
  uint32_t t = blockIdx.x * 256u + threadIdx.x;
  if (t >= 1572864u) return;
  uint32_t w    = t / 24576u;
  uint32_t rem  = t - w * 24576u;
  uint32_t h    = rem / 4096u;
  uint32_t rem2 = rem & 4095u;
  uint32_t stnt = rem2 >> 8, lane = (rem2 >> 2) & 63u, r = rem2 & 3u;
  uint32_t i = (stnt >> 2) * 16u + (lane >> 4) * 4u + r;
  uint32_t j = (stnt & 3u) * 16u + (lane & 15u);
  float v;
  if (j >= NTOK)      v = -1e30f;      // key-pad: forces softmax weight to 0
  else if (i >= NTOK) v = 0.f;         // query-pad rows are never stored
  else v = rpb[(uint32_t)rpi[i * NTOK + j] * NH + h] + mask[(size_t)w * (NTOK * NTOK) + i * NTOK + j];
  b5[t] = (bf16)v;
}

// ---- stage a 192x192 bf16 weight matrix into swizzled LDS ----
__device__ __forceinline__ void stage_w(char* lds, const bf16* __restrict__ w, uint32_t tid) {
  for (uint32_t u = tid; u < 4608u; u += 512u) {        // 16B units
    uint32_t row = u / 24u, c16 = u - row * 24u;
    uint4 v = *(const uint4*)(w + row * 192u + c16 * 8u);
    *(uint4*)(lds + row * 384u + ((c16 * 16u) ^ ((row & 7u) << 4))) = v;
  }
}

// ---- transpose acc tiles into LDS rows, then coalesced copy to global ----
__device__ __forceinline__ void store_tile_bf16(
    char* lds, const f32x4* acc, const float* __restrict__ bias_base,
    bf16* __restrict__ dst, uint32_t rowbase, uint32_t wv, uint32_t l15,
    uint32_t lg, uint32_t tid, float scale) {
  #pragma unroll
  for (uint32_t ntl = 0; ntl < 12u; ++ntl) {
    float bias = bias_base[ntl * 16u + l15];
    #pragma unroll
    for (uint32_t r = 0; r < 4u; ++r) {
      uint32_t trow = wv * 16u + lg * 4u + r;
      *(bf16*)(lds + trow * TSTRIDE + (ntl * 16u + l15) * 2u) =
          (bf16)((acc[ntl][r] + bias) * scale);
    }
  }
  __syncthreads();   // transpose tile ready
  for (uint32_t i = tid; i < 3072u; i += 512u) {        // 128 rows x 24 uint4
    uint32_t row = i / 24u, c16 = i - row * 24u;
    uint4 v = *(const uint4*)(lds + row * TSTRIDE + c16 * 16u);
    *(uint4*)(dst + (size_t)(rowbase + row) * CDIM + c16 * 8u) = v;
  }
}

// ---- Q GEMM: qo = (skip @ wskip^T + b) * scale, bf16. M=128/block ----
__global__ void __launch_bounds__(512, 4)
qgemm_kernel(const float* __restrict__ skip, const bf16* __restrict__ wskip_bf,
             const float* __restrict__ bskip, bf16* __restrict__ qo) {
  extern __shared__ char lds[];
  const uint32_t tid = threadIdx.x, lane = tid & 63u, wv = tid >> 6;
  const uint32_t l15 = lane & 15u, lg = lane >> 4;
  stage_w(lds, wskip_bf, tid);

  uint32_t rowbase = blockIdx.x * 128u;
  const float* ap = skip + (size_t)(rowbase + wv * 16u + l15) * CDIM + lg * 8u;
  bf16x8 af[6];
  #pragma unroll
  for (uint32_t kk = 0; kk < 6u; ++kk) af[kk] = lda8(ap + kk * 32u);
  __syncthreads();

  f32x4 acc[12] = {};
  #pragma unroll
  for (uint32_t kk = 0; kk < 6u; ++kk)
    #pragma unroll
    for (uint32_t ntl = 0; ntl < 12u; ++ntl) {
      bf16x8 wb = *(const bf16x8*)(lds + swz384(ntl * 16u + l15, kk * 64u + lg * 16u));
      acc[ntl] = __builtin_amdgcn_mfma_f32_16x16x32_bf16(af[kk], wb, acc[ntl], 0, 0, 0);
    }
  __syncthreads();   // W dead -> reuse region as transpose buffer
  store_tile_bf16(lds, acc, bskip, qo, rowbase, wv, l15, lg, tid, QSCALE);
}

// ---- KV GEMM: k,v = x @ wqkv^T + b, bf16. M=128/block ----
__global__ void __launch_bounds__(512, 4)
kvgemm_kernel(const float* __restrict__ x, const bf16* __restrict__ wqkv_bf,
              const float* __restrict__ bqkv, bf16* __restrict__ kbf,
              bf16* __restrict__ vbf) {
  extern __shared__ char lds[];
  const uint32_t tid = threadIdx.x, lane = tid & 63u, wv = tid >> 6;
  const uint32_t l15 = lane & 15u, lg = lane >> 4;

  uint32_t rowbase = blockIdx.x * 128u;
  const float* ap = x + (size_t)(rowbase + wv * 16u + l15) * CDIM + lg * 8u;
  bf16x8 af[6];
  #pragma unroll
  for (uint32_t kk = 0; kk < 6u; ++kk) af[kk] = lda8(ap + kk * 32u);

  #pragma unroll
  for (uint32_t h2 = 0; h2 < 2u; ++h2) {
    if (h2) __syncthreads();                 // copy-out of K done before restage
    stage_w(lds, wqkv_bf + h2 * 36864u, tid);
    __syncthreads();
    f32x4 acc[12] = {};
    #pragma unroll
    for (uint32_t kk = 0; kk < 6u; ++kk)
      #pragma unroll
      for (uint32_t ntl = 0; ntl < 12u; ++ntl) {
        bf16x8 wb = *(const bf16x8*)(lds + swz384(ntl * 16u + l15, kk * 64u + lg * 16u));
        acc[ntl] = __builtin_amdgcn_mfma_f32_16x16x32_bf16(af[kk], wb, acc[ntl], 0, 0, 0);
      }
    __syncthreads();   // W dead -> transpose buffer
    store_tile_bf16(lds, acc, bqkv + h2 * CDIM, h2 ? vbf : kbf, rowbase,
                    wv, l15, lg, tid, 1.0f);
  }
}

// ---- attention: one block per window, 512 thr. ----
__global__ void __launch_bounds__(512, 6)
attn_kernel(bf16* __restrict__ qo, const bf16* __restrict__ kbf,
            const bf16* __restrict__ vbf, const bf16* __restrict__ b5L) {
  extern __shared__ char lds[];
  const uint32_t tid = threadIdx.x, lane = tid & 63u, wv = tid >> 6;
  const uint32_t l15 = lane & 15u, lg = lane >> 4;
  const uint32_t grp = wv >> 2, st = wv & 3u;
  const uint32_t win = blockIdx.x;
  char* strip = lds + OFF_STRIP + wv * 2048u;
  const size_t wrow0 = (size_t)win * NTOK;

  // ---- stage V transposed: VT[ch][tok] at voff(ch), coalesced global reads ----
  for (uint32_t i = tid; i < 1176u; i += 512u) {         // 49 tok x 24 ch-chunks
    uint32_t tok = i / 24u, c16 = i - tok * 24u;
    uint4 v = *(const uint4*)(vbf + (wrow0 + tok) * CDIM + c16 * 8u);
    uint32_t u0 = v.x, u1 = v.y, u2 = v.z, u3 = v.w;
    uint32_t b0 = voff(c16 * 8u) + tok * 2u;             // ch>>4 constant across j
    *(uint16_t*)(lds + b0)          = (uint16_t)u0;
    *(uint16_t*)(lds + b0 + 144u)   = (uint16_t)(u0 >> 16);
    *(uint16_t*)(lds + b0 + 288u)   = (uint16_t)u1;
    *(uint16_t*)(lds + b0 + 432u)   = (uint16_t)(u1 >> 16);
    *(uint16_t*)(lds + b0 + 576u)   = (uint16_t)u2;
    *(uint16_t*)(lds + b0 + 720u)   = (uint16_t)(u2 >> 16);
    *(uint16_t*)(lds + b0 + 864u)   = (uint16_t)u3;
    *(uint16_t*)(lds + b0 + 1008u)  = (uint16_t)(u3 >> 16);
  }
  for (uint32_t i = tid; i < 2880u; i += 512u) {         // zero pad tokens 49..63
    uint32_t ch = i / 15u, tok = 49u + (i - ch * 15u);
    *(uint16_t*)(lds + voff(ch) + tok * 2u) = 0;
  }
  __syncthreads();

  f32x4 oacc[3][2];
  uint32_t qrow = st * 16u + l15; if (qrow > 48u) qrow = 48u;
  const uint32_t w6 = win & 63u;

  #pragma unroll
  for (uint32_t hl = 0; hl < 3u; ++hl) {
    uint32_t h = grp * 3u + hl;
    bf16x8 qa = *(const bf16x8*)(qo + (wrow0 + qrow) * CDIM + h * 32u + lg * 8u);
    f32x4 s[4];
    #pragma unroll
    for (uint32_t nt = 0; nt < 4u; ++nt) {
      uint32_t krow = nt * 16u + l15; if (krow > 48u) krow = 48u;
      bf16x8 kb = *(const bf16x8*)(kbf + (wrow0 + krow) * CDIM + h * 32u + lg * 8u);
      f32x4 z = {};
      s[nt] = __builtin_amdgcn_mfma_f32_16x16x32_bf16(qa, kb, z, 0, 0, 0);
    }
    // vectorized bias (+mask, pad pre-baked): 1 uint2 per nt
    const bf16* bp = b5L + ((((w6 * 6u + h) * 16u) + st * 4u) << 8) + lane * 4u;
    #pragma unroll
    for (uint32_t nt = 0; nt < 4u; ++nt) {
      uint2 bv = *(const uint2*)(bp + nt * 256u);
      s[nt][0] += bfu2f(bv.x);
      s[nt][1] += bfh2f(bv.x);
      s[nt][2] += bfu2f(bv.y);
      s[nt][3] += bfh2f(bv.y);
    }
    #pragma unroll
    for (uint32_t r = 0; r < 4u; ++r) {
      float mm = fmaxf(fmaxf(s[0][r], s[1][r]), fmaxf(s[2][r], s[3][r]));
      mm = fmaxf(mm, __shfl_xor(mm, 1)); mm = fmaxf(mm, __shfl_xor(mm, 2));
      mm = fmaxf(mm, __shfl_xor(mm, 4)); mm = fmaxf(mm, __shfl_xor(mm, 8));
      float ss = 0.f;
      #pragma unroll
      for (uint32_t nt = 0; nt < 4u; ++nt) { float p = __expf(s[nt][r] - mm); s[nt][r] = p; ss += p; }
      ss += __shfl_xor(ss, 1); ss += __shfl_xor(ss, 2);
      ss += __shfl_xor(ss, 4); ss += __shfl_xor(ss, 8);
      float inv = 1.f / ss;
      #pragma unroll
      for (uint32_t nt = 0; nt < 4u; ++nt) s[nt][r] *= inv;
    }
    // P (D-layout) -> private strip -> A-layout (same wave, no barrier)
    #pragma unroll
    for (uint32_t nt = 0; nt < 4u; ++nt) {
      uint32_t colb = (nt * 16u + l15) * 2u;
      #pragma unroll
      for (uint32_t r = 0; r < 4u; ++r)
        *(bf16*)(strip + swz128(lg * 4u + r, colb)) = (bf16)s[nt][r];
    }
    bf16x8 pa0 = *(const bf16x8*)(strip + swz128(l15, lg * 16u));
    bf16x8 pa1 = *(const bf16x8*)(strip + swz128(l15, 64u + lg * 16u));
    #pragma unroll
    for (uint32_t nt2 = 0; nt2 < 2u; ++nt2) {
      uint32_t ch = h * 32u + nt2 * 16u + l15;
      uint32_t va = voff(ch);
      bf16x8 vb0 = *(const bf16x8*)(lds + va + lg * 16u);
      bf16x8 vb1 = *(const bf16x8*)(lds + va + 64u + lg * 16u);
      f32x4 z = {};
      f32x4 o = __builtin_amdgcn_mfma_f32_16x16x32_bf16(pa0, vb0, z, 0, 0, 0);
      oacc[hl][nt2] = __builtin_amdgcn_mfma_f32_16x16x32_bf16(pa1, vb1, o, 0, 0, 0);
    }
  }

  __syncthreads();   // all V/Q reads done -> reuse VT region for O tile

  #pragma unroll
  for (uint32_t hl = 0; hl < 3u; ++hl)
    #pragma unroll
    for (uint32_t nt2 = 0; nt2 < 2u; ++nt2) {
      uint32_t ch = (grp * 3u + hl) * 32u + nt2 * 16u + l15;
      #pragma unroll
      for (uint32_t r = 0; r < 4u; ++r)
        *(bf16*)(lds + swz384(st * 16u + lg * 4u + r, ch * 2u)) = (bf16)oacc[hl][nt2][r];
    }

  __syncthreads();   // O tile ready -> coalesced write over Q

  for (uint32_t i = tid; i < 1176u; i += 512u) {
    uint32_t tok = i / 24u, c16 = i - tok * 24u;
    uint4 v = *(const uint4*)(lds + swz384(tok, c16 * 16u));
    *(uint4*)(qo + (wrow0 + tok) * CDIM + c16 * 8u) = v;
  }
}

// ---- proj GEMM: out = O @ wproj^T + b, f32. M=128/block, direct stores ----
__global__ void __launch_bounds__(512, 4)
proj_kernel(const bf16* __restrict__ qo, const bf16* __restrict__ wproj_bf,
            const float* __restrict__ bproj, float* __restrict__ out) {
  extern __shared__ char lds[];
  const uint32_t tid = threadIdx.x, lane = tid & 63u, wv = tid >> 6;
  const uint32_t l15 = lane & 15u, lg = lane >> 4;
  stage_w(lds, wproj_bf, tid);

  uint32_t rowbase = blockIdx.x * 128u;
  const bf16* ap = qo + (size_t)(rowbase + wv * 16u + l15) * CDIM + lg * 8u;
  bf16x8 af[6];
  #pragma unroll
  for (uint32_t kk = 0; kk < 6u; ++kk) af[kk] = *(const bf16x8*)(ap + kk * 32u);
  __syncthreads();

  f32x4 acc[12] = {};
  #pragma unroll
  for (uint32_t kk = 0; kk < 6u; ++kk)
    #pragma unroll
    for (uint32_t ntl = 0; ntl < 12u; ++ntl) {
      bf16x8 wb = *(const bf16x8*)(lds + swz384(ntl * 16u + l15, kk * 64u + lg * 16u));
      acc[ntl] = __builtin_amdgcn_mfma_f32_16x16x32_bf16(af[kk], wb, acc[ntl], 0, 0, 0);
    }
  #pragma unroll
  for (uint32_t ntl = 0; ntl < 12u; ++ntl) {
    uint32_t ch = ntl * 16u + l15;
    float bias = bproj[ch];
    #pragma unroll
    for (uint32_t r = 0; r < 4u; ++r) {
      uint32_t row = rowbase + wv * 16u + lg * 4u + r;
      out[(size_t)row * CDIM + ch] = acc[ntl][r] + bias;
    }
  }
}

extern "C" void kernel_launch(void* const* d_in, const int* in_sizes, int n_in,
                              void* d_out, int out_size, void* d_ws, size_t ws_size,
                              hipStream_t stream) {
  const float* x     = (const float*)d_in[0];
  const float* skip  = (const float*)d_in[1];
  const float* mask  = (const float*)d_in[2];
  const int*   rpi   = (const int*)  d_in[3];
  const float* rpb   = (const float*)d_in[4];
  const float* wqkv  = (const float*)d_in[5];
  const float* bqkv  = (const float*)d_in[6];
  const float* wskip = (const float*)d_in[7];
  const float* bskip = (const float*)d_in[8];
  const float* wproj = (const float*)d_in[9];
  const float* bproj = (const float*)d_in[10];

  char* ws = (char*)d_ws;
  bf16* wbf  = (bf16*)(ws + WSB_W);
  bf16* b5L  = (bf16*)(ws + WSB_B5);
  bf16* qo   = (bf16*)(ws + WSB_QO);
  bf16* kbf  = (bf16*)(ws + WSB_K);
  bf16* vbf  = (bf16*)(ws + WSB_V);

  uint32_t nwin  = (uint32_t)(in_sizes[0] / (NTOK * CDIM));
  uint32_t nrows = nwin * NTOK;            // 200704, divisible by 128
  uint32_t ngb   = nrows / 128u;

  hipFuncSetAttribute((const void*)qgemm_kernel,  hipFuncAttributeMaxDynamicSharedMemorySize, 73728);
  hipFuncSetAttribute((const void*)kvgemm_kernel, hipFuncAttributeMaxDynamicSharedMemorySize, 73728);
  hipFuncSetAttribute((const void*)proj_kernel,   hipFuncAttributeMaxDynamicSharedMemorySize, 73728);

  wcvt_kernel<<<144, 256, 0, stream>>>(wqkv, wskip, wproj, wbf);
  biasprep_kernel<<<6144, 256, 0, stream>>>(rpi, rpb, mask, b5L);
  qgemm_kernel<<<ngb, 512, 73728, stream>>>(skip, wbf + WSE_WSKIP, bskip, qo);
  kvgemm_kernel<<<ngb, 512, 73728, stream>>>(x, wbf, bqkv, kbf, vbf);
  attn_kernel<<<nwin, 512, ATTN_LDS, stream>>>(qo, kbf, vbf, b5L);
  proj_kernel<<<ngb, 512, 73728, stream>>>(qo, wbf + WSE_WPROJ, bproj, (float*)d_out);
}

// Round 9
// 325.958 us; speedup vs baseline: 1.6032x; 1.0937x over previous
//
#include <hip/hip_runtime.h>
#include <hip/hip_bf16.h>
#include <stdint.h>

// WindowMSA, round 9: attn rewritten with double-swapped MFMAs.
//  - QK^T computed as S^T = mfma(K,Q): lane owns one q-row (q=lane&15) ->
//    softmax is 15 in-reg fmax + 2 shfl (xor16,32) instead of 32 shfl/hl.
//  - P^T staged with 4x ds_write_b64 (was 16 scalar u16); read back b128.
//  - PV computed as O^T = mfma(V^T, P^T): lane gets 4 consecutive d values
//    per register -> O staged with 2x b64 per (hl,nt2) (was 24 scalar u16).
//  - V staging pair-packs two tokens per b32 write (8 b32 per uint4, was 16 u16).
//  - bias5d re-laid out for the transposed S: j = nt*16 + (lane>>4)*4 + r.
// GEMMs identical to round 8.

typedef __bf16 bf16;
typedef __attribute__((ext_vector_type(8))) __bf16 bf16x8;
typedef __attribute__((ext_vector_type(4))) float f32x4;

#define CDIM 192
#define NH 6
#define NTOK 49
#define QSCALE 0.17677669529663687f

// ws byte offsets
#define WSB_W      0u          // 147456 bf16 = 294912 B (wqkv | wskip | wproj)
#define WSE_WSKIP  73728u
#define WSE_WPROJ  110592u
#define WSB_B5     294912u     // b5L: 64*6*16*256 bf16 = 3,145,728 B
#define WSB_QO     3440640u    // 200704*192 bf16 = 77,070,336 B (Q, then O)
#define WSB_K      80510976u
#define WSB_V      157581312u  // end 234,651,648

#define TSTRIDE 400u           // GEMM transpose buffer row stride

// attn LDS: VT region 27904 (voff(191)+128 = 27808), 8 strips of 2304
#define OFF_STRIP 27904u
#define STRIPB    2304u
#define ATTN_LDS  46336u       // 27904 + 8*2304
#define OSTRIDE   400u         // O tile row stride (reuses VT region)

__device__ __forceinline__ uint32_t swz384(uint32_t row, uint32_t b) {
  return row * 384u + (b ^ ((row & 7u) << 4));
}
__device__ __forceinline__ uint32_t voff(uint32_t ch) {   // VT row base, 16B-aligned, monotone
  return ch * 144u + ((ch >> 4) << 4);
}
__device__ __forceinline__ uint32_t f2u(float f) { bf16 h = (bf16)f; return (uint32_t)__builtin_bit_cast(uint16_t, h); }
__device__ __forceinline__ bf16x8 lda8(const float* p) {
  float4 w0 = *(const float4*)p;
  float4 w1 = *(const float4*)(p + 4);
  bf16x8 b = {(bf16)w0.x, (bf16)w0.y, (bf16)w0.z, (bf16)w0.w,
              (bf16)w1.x, (bf16)w1.y, (bf16)w1.z, (bf16)w1.w};
  return b;
}
__device__ __forceinline__ float bfu2f(uint32_t lo16) { return __builtin_bit_cast(float, lo16 << 16); }
__device__ __forceinline__ float bfh2f(uint32_t hi16) { return __builtin_bit_cast(float, hi16 & 0xffff0000u); }

// ---- weights f32 -> bf16 ----
__global__ void __launch_bounds__(256)
wcvt_kernel(const float* __restrict__ wqkv, const float* __restrict__ wskip,
            const float* __restrict__ wproj, bf16* __restrict__ ws) {
  uint32_t i = (blockIdx.x * 256u + threadIdx.x) * 4u;
  float4 v;
  if (i < 73728u)       v = *(const float4*)(wqkv + i);
  else if (i < 110592u) v = *(const float4*)(wskip + (i - 73728u));
  else                  v = *(const float4*)(wproj + (i - 110592u));
  *(uint2*)(ws + i) = make_uint2((f2u(v.y) << 16) | f2u(v.x), (f2u(v.w) << 16) | f2u(v.z));
}

// ---- bias for transposed S: t = (((w*6+h)*16 + st*4+nt)*64 + lane)*4 + r
//      i (query) = st*16 + (lane&15) ; j (key) = nt*16 + (lane>>4)*4 + r ----
__global__ void __launch_bounds__(256)
biasprep_kernel(const int* __restrict__ rpi, const float* __restrict__ rpb,
                const float* __restrict__ mask, bf16* __restrict__ b5) {
  uint32_t t = blockIdx.x * 256u + threadIdx.x;
  if (t >= 1572864u) return;
  uint32_t w    = t / 24576u;
  uint32_t rem  = t - w * 24576u;
  uint32_t h    = rem / 4096u;
  uint32_t rem2 = rem & 4095u;
  uint32_t stnt = rem2 >> 8, lane = (rem2 >> 2) & 63u, r = rem2 & 3u;
  uint32_t i = (stnt >> 2) * 16u + (lane & 15u);
  uint32_t j = (stnt & 3u) * 16u + (lane >> 4) * 4u + r;
  float v;
  if (j >= NTOK)      v = -1e30f;      // key-pad: softmax weight -> 0
  else if (i >= NTOK) v = 0.f;         // query-pad rows are never stored
  else v = rpb[(uint32_t)rpi[i * NTOK + j] * NH + h] + mask[(size_t)w * (NTOK * NTOK) + i * NTOK + j];
  b5[t] = (bf16)v;
}

// ---- stage a 192x192 bf16 weight matrix into swizzled LDS ----
__device__ __forceinline__ void stage_w(char* lds, const bf16* __restrict__ w, uint32_t tid) {
  for (uint32_t u = tid; u < 4608u; u += 512u) {        // 16B units
    uint32_t row = u / 24u, c16 = u - row * 24u;
    uint4 v = *(const uint4*)(w + row * 192u + c16 * 8u);
    *(uint4*)(lds + row * 384u + ((c16 * 16u) ^ ((row & 7u) << 4))) = v;
  }
}

// ---- transpose acc tiles into LDS rows, then coalesced copy to global ----
__device__ __forceinline__ void store_tile_bf16(
    char* lds, const f32x4* acc, const float* __restrict__ bias_base,
    bf16* __restrict__ dst, uint32_t rowbase, uint32_t wv, uint32_t l15,
    uint32_t lg, uint32_t tid, float scale) {
  #pragma unroll
  for (uint32_t ntl = 0; ntl < 12u; ++ntl) {
    float bias = bias_base[ntl * 16u + l15];
    #pragma unroll
    for (uint32_t r = 0; r < 4u; ++r) {
      uint32_t trow = wv * 16u + lg * 4u + r;
      *(bf16*)(lds + trow * TSTRIDE + (ntl * 16u + l15) * 2u) =
          (bf16)((acc[ntl][r] + bias) * scale);
    }
  }
  __syncthreads();   // transpose tile ready
  for (uint32_t i = tid; i < 3072u; i += 512u) {        // 128 rows x 24 uint4
    uint32_t row = i / 24u, c16 = i - row * 24u;
    uint4 v = *(const uint4*)(lds + row * TSTRIDE + c16 * 16u);
    *(uint4*)(dst + (size_t)(rowbase + row) * CDIM + c16 * 8u) = v;
  }
}

// ---- Q GEMM: qo = (skip @ wskip^T + b) * scale, bf16. M=128/block ----
__global__ void __launch_bounds__(512, 4)
qgemm_kernel(const float* __restrict__ skip, const bf16* __restrict__ wskip_bf,
             const float* __restrict__ bskip, bf16* __restrict__ qo) {
  extern __shared__ char lds[];
  const uint32_t tid = threadIdx.x, lane = tid & 63u, wv = tid >> 6;
  const uint32_t l15 = lane & 15u, lg = lane >> 4;
  stage_w(lds, wskip_bf, tid);

  uint32_t rowbase = blockIdx.x * 128u;
  const float* ap = skip + (size_t)(rowbase + wv * 16u + l15) * CDIM + lg * 8u;
  bf16x8 af[6];
  #pragma unroll
  for (uint32_t kk = 0; kk < 6u; ++kk) af[kk] = lda8(ap + kk * 32u);
  __syncthreads();

  f32x4 acc[12] = {};
  #pragma unroll
  for (uint32_t kk = 0; kk < 6u; ++kk)
    #pragma unroll
    for (uint32_t ntl = 0; ntl < 12u; ++ntl) {
      bf16x8 wb = *(const bf16x8*)(lds + swz384(ntl * 16u + l15, kk * 64u + lg * 16u));
      acc[ntl] = __builtin_amdgcn_mfma_f32_16x16x32_bf16(af[kk], wb, acc[ntl], 0, 0, 0);
    }
  __syncthreads();   // W dead -> reuse region as transpose buffer
  store_tile_bf16(lds, acc, bskip, qo, rowbase, wv, l15, lg, tid, QSCALE);
}

// ---- KV GEMM: k,v = x @ wqkv^T + b, bf16. M=128/block ----
__global__ void __launch_bounds__(512, 4)
kvgemm_kernel(const float* __restrict__ x, const bf16* __restrict__ wqkv_bf,
              const float* __restrict__ bqkv, bf16* __restrict__ kbf,
              bf16* __restrict__ vbf) {
  extern __shared__ char lds[];
  const uint32_t tid = threadIdx.x, lane = tid & 63u, wv = tid >> 6;
  const uint32_t l15 = lane & 15u, lg = lane >> 4;

  uint32_t rowbase = blockIdx.x * 128u;
  const float* ap = x + (size_t)(rowbase + wv * 16u + l15) * CDIM + lg * 8u;
  bf16x8 af[6];
  #pragma unroll
  for (uint32_t kk = 0; kk < 6u; ++kk) af[kk] = lda8(ap + kk * 32u);

  #pragma unroll
  for (uint32_t h2 = 0; h2 < 2u; ++h2) {
    if (h2) __syncthreads();                 // copy-out of K done before restage
    stage_w(lds, wqkv_bf + h2 * 36864u, tid);
    __syncthreads();
    f32x4 acc[12] = {};
    #pragma unroll
    for (uint32_t kk = 0; kk < 6u; ++kk)
      #pragma unroll
      for (uint32_t ntl = 0; ntl < 12u; ++ntl) {
        bf16x8 wb = *(const bf16x8*)(lds + swz384(ntl * 16u + l15, kk * 64u + lg * 16u));
        acc[ntl] = __builtin_amdgcn_mfma_f32_16x16x32_bf16(af[kk], wb, acc[ntl], 0, 0, 0);
      }
    __syncthreads();   // W dead -> transpose buffer
    store_tile_bf16(lds, acc, bqkv + h2 * CDIM, h2 ? vbf : kbf, rowbase,
                    wv, l15, lg, tid, 1.0f);
  }
}

// ---- attention: one block per window, 512 thr, swapped-MFMA structure ----
__global__ void __launch_bounds__(512, 6)
attn_kernel(bf16* __restrict__ qo, const bf16* __restrict__ kbf,
            const bf16* __restrict__ vbf, const bf16* __restrict__ b5L) {
  extern __shared__ char lds[];
  const uint32_t tid = threadIdx.x, lane = tid & 63u, wv = tid >> 6;
  const uint32_t l15 = lane & 15u, lg = lane >> 4;
  const uint32_t grp = wv >> 2, st = wv & 3u;
  const uint32_t win = blockIdx.x;
  char* strip = lds + OFF_STRIP + wv * STRIPB;
  const size_t wrow0 = (size_t)win * NTOK;

  // ---- stage V transposed, tok-pair packed b32 writes ----
  for (uint32_t i = tid; i < 600u; i += 512u) {          // 25 pairs x 24 c16
    uint32_t pair = i / 24u, c16 = i - pair * 24u;
    uint32_t tok0 = pair * 2u;                           // 0,2,..,48
    const bf16* src = vbf + (wrow0 + tok0) * CDIM + c16 * 8u;
    uint4 a = *(const uint4*)src;
    uint4 b = make_uint4(0u, 0u, 0u, 0u);
    if (tok0 + 1u < NTOK) b = *(const uint4*)(src + CDIM);
    uint32_t base = voff(c16 * 8u) + tok0 * 2u;          // ch>>4 const over the 8 chans
    uint32_t aw[4] = {a.x, a.y, a.z, a.w};
    uint32_t bw[4] = {b.x, b.y, b.z, b.w};
    #pragma unroll
    for (uint32_t q = 0; q < 4u; ++q) {
      // channels c16*8 + 2q (low halves) and +2q+1 (high halves)
      *(uint32_t*)(lds + base + (2u * q) * 144u)      = (aw[q] & 0xffffu) | (bw[q] << 16);
      *(uint32_t*)(lds + base + (2u * q + 1u) * 144u) = (aw[q] >> 16) | (bw[q] & 0xffff0000u);
    }
  }
  for (uint32_t i = tid; i < 1344u; i += 512u) {         // zero toks 50..63 (49 done above)
    uint32_t ch = i / 7u, p = i - ch * 7u;
    *(uint32_t*)(lds + voff(ch) + (50u + p * 2u) * 2u) = 0u;
  }
  __syncthreads();

  f32x4 oacc[3][2];
  uint32_t qrow = st * 16u + l15; if (qrow > 48u) qrow = 48u;
  const uint32_t w6 = win & 63u;

  #pragma unroll
  for (uint32_t hl = 0; hl < 3u; ++hl) {
    uint32_t h = grp * 3u + hl;
    // Q as B-fragment (col = q = l15), K as A-fragment (row = k = l15)
    bf16x8 qb = *(const bf16x8*)(qo + (wrow0 + qrow) * CDIM + h * 32u + lg * 8u);
    f32x4 s[4];
    #pragma unroll
    for (uint32_t nt = 0; nt < 4u; ++nt) {
      uint32_t krow = nt * 16u + l15; if (krow > 48u) krow = 48u;
      bf16x8 ka = *(const bf16x8*)(kbf + (wrow0 + krow) * CDIM + h * 32u + lg * 8u);
      f32x4 z = {};
      s[nt] = __builtin_amdgcn_mfma_f32_16x16x32_bf16(ka, qb, z, 0, 0, 0);
    }
    // bias: lane's q row, k = nt*16 + lg*4 + r (baked layout)
    const bf16* bp = b5L + ((((w6 * 6u + h) * 16u) + st * 4u) << 8) + lane * 4u;
    #pragma unroll
    for (uint32_t nt = 0; nt < 4u; ++nt) {
      uint2 bv = *(const uint2*)(bp + nt * 256u);
      s[nt][0] += bfu2f(bv.x);
      s[nt][1] += bfh2f(bv.x);
      s[nt][2] += bfu2f(bv.y);
      s[nt][3] += bfh2f(bv.y);
    }
    // softmax over the lane's 16 scores + cross-lg reduce (2 shfl each)
    float mm = s[0][0];
    #pragma unroll
    for (uint32_t nt = 0; nt < 4u; ++nt)
      #pragma unroll
      for (uint32_t r = 0; r < 4u; ++r) mm = fmaxf(mm, s[nt][r]);
    mm = fmaxf(mm, __shfl_xor(mm, 16)); mm = fmaxf(mm, __shfl_xor(mm, 32));
    float ss = 0.f;
    #pragma unroll
    for (uint32_t nt = 0; nt < 4u; ++nt)
      #pragma unroll
      for (uint32_t r = 0; r < 4u; ++r) { float p = __expf(s[nt][r] - mm); s[nt][r] = p; ss += p; }
    ss += __shfl_xor(ss, 16); ss += __shfl_xor(ss, 32);
    float inv = 1.f / ss;
    // P store: lane's 4 consecutive k per nt -> b64 into strip[q=l15][k]
    #pragma unroll
    for (uint32_t nt = 0; nt < 4u; ++nt) {
      uint2 w;
      w.x = (f2u(s[nt][1] * inv) << 16) | f2u(s[nt][0] * inv);
      w.y = (f2u(s[nt][3] * inv) << 16) | f2u(s[nt][2] * inv);
      *(uint2*)(strip + l15 * 144u + nt * 32u + lg * 8u) = w;
    }
    // P^T B-fragments (col = q = l15, k = lg*8+j), b128 reads
    bf16x8 pb0 = *(const bf16x8*)(strip + l15 * 144u + lg * 16u);
    bf16x8 pb1 = *(const bf16x8*)(strip + l15 * 144u + 64u + lg * 16u);
    // PV: O^T = V^T(A, row=d=l15) x P^T(B) ; D: lane q=l15, d=lg*4+r consec.
    #pragma unroll
    for (uint32_t nt2 = 0; nt2 < 2u; ++nt2) {
      uint32_t ch = h * 32u + nt2 * 16u + l15;
      uint32_t va = voff(ch);
      bf16x8 va0 = *(const bf16x8*)(lds + va + lg * 16u);
      bf16x8 va1 = *(const bf16x8*)(lds + va + 64u + lg * 16u);
      f32x4 z = {};
      f32x4 o = __builtin_amdgcn_mfma_f32_16x16x32_bf16(va0, pb0, z, 0, 0, 0);
      oacc[hl][nt2] = __builtin_amdgcn_mfma_f32_16x16x32_bf16(va1, pb1, o, 0, 0, 0);
    }
  }

  __syncthreads();   // all VT/strip reads done -> reuse VT region as O tile

  // O tile [tok][ch] stride OSTRIDE; lane q = st*16+l15, 4 consecutive d -> b64
  {
    uint32_t orow = (st * 16u + l15) * OSTRIDE;
    #pragma unroll
    for (uint32_t hl = 0; hl < 3u; ++hl)
      #pragma unroll
      for (uint32_t nt2 = 0; nt2 < 2u; ++nt2) {
        uint32_t d0 = (grp * 3u + hl) * 32u + nt2 * 16u + lg * 4u;
        uint2 w;
        w.x = (f2u(oacc[hl][nt2][1]) << 16) | f2u(oacc[hl][nt2][0]);
        w.y = (f2u(oacc[hl][nt2][3]) << 16) | f2u(oacc[hl][nt2][2]);
        *(uint2*)(lds + orow + d0 * 2u) = w;
      }
  }

  __syncthreads();   // O tile ready -> coalesced write over Q

  for (uint32_t i = tid; i < 1176u; i += 512u) {
    uint32_t tok = i / 24u, c16 = i - tok * 24u;
    uint4 v = *(const uint4*)(lds + tok * OSTRIDE + c16 * 16u);
    *(uint4*)(qo + (wrow0 + tok) * CDIM + c16 * 8u) = v;
  }
}

// ---- proj GEMM: out = O @ wproj^T + b, f32. M=128/block, direct stores ----
__global__ void __launch_bounds__(512, 4)
proj_kernel(const bf16* __restrict__ qo, const bf16* __restrict__ wproj_bf,
            const float* __restrict__ bproj, float* __restrict__ out) {
  extern __shared__ char lds[];
  const uint32_t tid = threadIdx.x, lane = tid & 63u, wv = tid >> 6;
  const uint32_t l15 = lane & 15u, lg = lane >> 4;
  stage_w(lds, wproj_bf, tid);

  uint32_t rowbase = blockIdx.x * 128u;
  const bf16* ap = qo + (size_t)(rowbase + wv * 16u + l15) * CDIM + lg * 8u;
  bf16x8 af[6];
  #pragma unroll
  for (uint32_t kk = 0; kk < 6u; ++kk) af[kk] = *(const bf16x8*)(ap + kk * 32u);
  __syncthreads();

  f32x4 acc[12] = {};
  #pragma unroll
  for (uint32_t kk = 0; kk < 6u; ++kk)
    #pragma unroll
    for (uint32_t ntl = 0; ntl < 12u; ++ntl) {
      bf16x8 wb = *(const bf16x8*)(lds + swz384(ntl * 16u + l15, kk * 64u + lg * 16u));
      acc[ntl] = __builtin_amdgcn_mfma_f32_16x16x32_bf16(af[kk], wb, acc[ntl], 0, 0, 0);
    }
  #pragma unroll
  for (uint32_t ntl = 0; ntl < 12u; ++ntl) {
    uint32_t ch = ntl * 16u + l15;
    float bias = bproj[ch];
    #pragma unroll
    for (uint32_t r = 0; r < 4u; ++r) {
      uint32_t row = rowbase + wv * 16u + lg * 4u + r;
      out[(size_t)row * CDIM + ch] = acc[ntl][r] + bias;
    }
  }
}

extern "C" void kernel_launch(void* const* d_in, const int* in_sizes, int n_in,
                              void* d_out, int out_size, void* d_ws, size_t ws_size,
                              hipStream_t stream) {
  const float* x     = (const float*)d_in[0];
  const float* skip  = (const float*)d_in[1];
  const float* mask  = (const float*)d_in[2];
  const int*   rpi   = (const int*)  d_in[3];
  const float* rpb   = (const float*)d_in[4];
  const float* wqkv  = (const float*)d_in[5];
  const float* bqkv  = (const float*)d_in[6];
  const float* wskip = (const float*)d_in[7];
  const float* bskip = (const float*)d_in[8];
  const float* wproj = (const float*)d_in[9];
  const float* bproj = (const float*)d_in[10];

  char* ws = (char*)d_ws;
  bf16* wbf  = (bf16*)(ws + WSB_W);
  bf16* b5L  = (bf16*)(ws + WSB_B5);
  bf16* qo   = (bf16*)(ws + WSB_QO);
  bf16* kbf  = (bf16*)(ws + WSB_K);
  bf16* vbf  = (bf16*)(ws + WSB_V);

  uint32_t nwin  = (uint32_t)(in_sizes[0] / (NTOK * CDIM));
  uint32_t nrows = nwin * NTOK;            // 200704, divisible by 128
  uint32_t ngb   = nrows / 128u;

  hipFuncSetAttribute((const void*)qgemm_kernel,  hipFuncAttributeMaxDynamicSharedMemorySize, 73728);
  hipFuncSetAttribute((const void*)kvgemm_kernel, hipFuncAttributeMaxDynamicSharedMemorySize, 73728);
  hipFuncSetAttribute((const void*)proj_kernel,   hipFuncAttributeMaxDynamicSharedMemorySize, 73728);
  hipFuncSetAttribute((const void*)attn_kernel,   hipFuncAttributeMaxDynamicSharedMemorySize, (int)ATTN_LDS);

  wcvt_kernel<<<144, 256, 0, stream>>>(wqkv, wskip, wproj, wbf);
  biasprep_kernel<<<6144, 256, 0, stream>>>(rpi, rpb, mask, b5L);
  qgemm_kernel<<<ngb, 512, 73728, stream>>>(skip, wbf + WSE_WSKIP, bskip, qo);
  kvgemm_kernel<<<ngb, 512, 73728, stream>>>(x, wbf, bqkv, kbf, vbf);
  attn_kernel<<<nwin, 512, ATTN_LDS, stream>>>(qo, kbf, vbf, b5L);
  proj_kernel<<<ngb, 512, 73728, stream>>>(qo, wbf + WSE_WPROJ, bproj, (float*)d_out);
}